// Round 14
// baseline (182.266 us; speedup 1.0000x reference)
//
#include <hip/hip_runtime.h>

#define NF 128   // in/hidden features
#define NC 64    // classes
#define SLICES 64

typedef short bf16x8 __attribute__((ext_vector_type(8)));
typedef float f32x4 __attribute__((ext_vector_type(4)));

__device__ __forceinline__ unsigned f2bf(float f) {   // fp32 -> bf16 (RTN)
    unsigned u = __float_as_uint(f);
    return (u + 0x7FFFu + ((u >> 16) & 1u)) >> 16;
}
__device__ __forceinline__ float bf2f(unsigned h) { return __uint_as_float(h << 16); }

// ---- fused prep: count_rank blocks + weight-transpose blocks + X->bf16 cast blocks ----
__global__ __launch_bounds__(256) void prep_fused(const int* __restrict__ col,
                                                  unsigned short* __restrict__ eoff16,
                                                  unsigned short* __restrict__ C16,
                                                  const float* __restrict__ W1,
                                                  const float* __restrict__ W2,
                                                  unsigned short* __restrict__ Wt1,
                                                  unsigned short* __restrict__ Wt2,
                                                  const float* __restrict__ X,
                                                  unsigned* __restrict__ Xb2,
                                                  int N, int E, int SL, int nh,
                                                  int CRB, int WTB, int XCB) {
    __shared__ unsigned hist[12544];
    const int b = blockIdx.x;
    const int tid = threadIdx.x;
    if (b < CRB) {
        const int j = b >> 1;
        const int h = b & 1;
        const int nlo = h * nh;
        const int nhi = min(N, nlo + nh);
        const int words = (nhi - nlo + 1) >> 1;
        for (int i = tid; i < words; i += 256) hist[i] = 0;
        __syncthreads();
        const int e0 = j * SL, e1 = min(E, e0 + SL);
        for (int e = e0 + tid; e < e1; e += 256) {
            int c = col[e];
            if (c >= nlo && c < nhi) {
                int cl = c - nlo;
                unsigned sh = (cl & 1) * 16;
                unsigned old = atomicAdd(&hist[cl >> 1], 1u << sh);
                eoff16[e] = (unsigned short)((old >> sh) & 0xffffu);
            }
        }
        __syncthreads();
        unsigned* Cw = (unsigned*)(C16 + (size_t)j * N + nlo);
        for (int i = tid; i < words; i += 256) Cw[i] = hist[i];
    } else if (b < CRB + WTB) {
        int i = (b - CRB) * 256 + tid;
        if (i < 128 * 128) {
            int k = i >> 7, n = i & 127;
            Wt1[n * 128 + k] = (unsigned short)f2bf(W1[i]);
        } else {
            int j = i - 128 * 128;
            if (j < 128 * 64) {
                int k = j >> 6, n = j & 63;
                Wt2[n * 128 + k] = (unsigned short)f2bf(W2[j]);
            }
        }
    } else {
        const float4* X4 = (const float4*)X;
        uint2* O = (uint2*)Xb2;
        int items = N * 32;
        for (int i = (b - CRB - WTB) * 256 + tid; i < items; i += XCB * 256) {
            float4 v = X4[i];
            O[i] = make_uint2(f2bf(v.x) | (f2bf(v.y) << 16),
                              f2bf(v.z) | (f2bf(v.w) << 16));
        }
    }
}

// ---- merged: per-node slice scan (C16 in place) + 256-node block scan -> excl, bsum ----
__global__ __launch_bounds__(256) void scanCB(unsigned short* __restrict__ C16,
                                              int* __restrict__ excl,
                                              int* __restrict__ bsum, int N) {
    __shared__ int sh[256];
    int t = threadIdx.x;
    int n = blockIdx.x * 256 + t;
    int run = 0;
    if (n < N) {
#pragma unroll 4
        for (int j = 0; j < SLICES; ++j) {
            size_t idx = (size_t)j * N + n;
            int v = C16[idx];
            C16[idx] = (unsigned short)run;
            run += v;
        }
    }
    sh[t] = run;
    __syncthreads();
    for (int off = 1; off < 256; off <<= 1) {
        int x = (t >= off) ? sh[t - off] : 0;
        __syncthreads();
        sh[t] += x;
        __syncthreads();
    }
    int incl = sh[t];
    if (t == 255) bsum[blockIdx.x] = incl;
    if (n < N) excl[n] = incl - run;
}

__global__ void scan_sums(int* __restrict__ bsum, int nb) {
    int run = 0;
    for (int i = 0; i < nb; ++i) { int v = bsum[i]; bsum[i] = run; run += v; }
    bsum[nb] = run;
}

__global__ __launch_bounds__(256) void scan_add(int* __restrict__ excl,
                                                const int* __restrict__ bsum,
                                                int N, int nb) {
    int i = blockIdx.x * 256 + threadIdx.x;
    if (i < N) excl[i] += bsum[i >> 8];
    if (i == 0) excl[N] = bsum[nb];
}

// ---- fused: slice-aligned scatter (packed 4B entries, no atomics) + MFMA gemm1 ----
__global__ __launch_bounds__(256) void scatter_gemm1_fused(const int* __restrict__ row,
                                                           const int* __restrict__ col,
                                                           const float* __restrict__ ew,
                                                           const int* __restrict__ rowPtr,
                                                           const unsigned short* __restrict__ Coff16,
                                                           const unsigned short* __restrict__ eoff16,
                                                           unsigned* __restrict__ csru,
                                                           const unsigned short* __restrict__ Xb,  // [N][128] bf16
                                                           const unsigned short* __restrict__ Wt1,
                                                           unsigned short* __restrict__ H,  // [N][128] bf16
                                                           int N, int E, int SL, int SB) {
    __shared__ char XsB[16384];   // 64 rows x 128 k bf16, XOR-swizzled
    __shared__ char WsB[32768];   // 128 n  x 128 k bf16, XOR-swizzled
    const int tid = threadIdx.x;
    if ((int)blockIdx.x < SB) {
        const int j = blockIdx.x >> 3;
        const int sub = blockIdx.x & 7;
        const int e0 = j * SL, e1 = min(E, e0 + SL);
        const int per = ((e1 - e0) + 7) >> 3;
        const int lo = min(e1, e0 + sub * per);
        const int hi = min(e1, lo + per);
        const unsigned short* Crow = Coff16 + (size_t)j * N;
        for (int e = lo + tid; e < hi; e += 256) {
            int c = col[e];
            int idx = rowPtr[c] + (int)Crow[c] + (int)eoff16[e];
            csru[idx] = ((unsigned)row[e] << 16) | f2bf(ew[e]);
        }
        return;
    }
    const int bm0 = ((int)blockIdx.x - SB) * 64;
    {
        int r = tid >> 2, q4 = (tid & 3) * 4;
        const uint4* src = (const uint4*)(Xb + (size_t)min(bm0 + r, N - 1) * 128);
#pragma unroll
        for (int qq = 0; qq < 4; ++qq) {
            int kb = (q4 + qq) * 16;
            *(uint4*)(XsB + r * 256 + (kb ^ ((r & 7) << 4))) = src[q4 + qq];
        }
    }
    {
        const uint4* src = (const uint4*)Wt1;
#pragma unroll
        for (int t = 0; t < 8; ++t) {
            int i = t * 256 + tid;
            int n = i >> 4, kb = (i & 15) * 16;
            *(uint4*)(WsB + n * 256 + (kb ^ ((n & 7) << 4))) = src[i];
        }
    }
    __syncthreads();
    const int w = tid >> 6, l = tid & 63;
    const int lr = l & 15, lg = l >> 4;
    f32x4 acc[8] = {};
#pragma unroll
    for (int kk = 0; kk < 4; ++kk) {
        int r = w * 16 + lr;
        bf16x8 a = *(const bf16x8*)(XsB + r * 256 + ((kk * 64 + lg * 16) ^ ((r & 7) << 4)));
        bf16x8 b[8];
#pragma unroll
        for (int nt = 0; nt < 8; ++nt) {
            int n = nt * 16 + lr;
            b[nt] = *(const bf16x8*)(WsB + n * 256 + ((kk * 64 + lg * 16) ^ ((n & 7) << 4)));
        }
#pragma unroll
        for (int nt = 0; nt < 8; ++nt)
            acc[nt] = __builtin_amdgcn_mfma_f32_16x16x32_bf16(a, b[nt], acc[nt], 0, 0, 0);
    }
#pragma unroll
    for (int reg = 0; reg < 4; ++reg) {
        int node = bm0 + w * 16 + lg * 4 + reg;
        if (node < N) {
#pragma unroll
            for (int nt = 0; nt < 8; ++nt)
                H[(size_t)node * 128 + nt * 16 + lr] = (unsigned short)f2bf(acc[nt][reg]);
        }
    }
}

// ---- MFMA gemm2: H3[N x 64 bf16] = A(bf16 [N][128]) @ W2 ----
__global__ __launch_bounds__(256) void gemm2_mfma(const unsigned short* __restrict__ A,
                                                  const unsigned short* __restrict__ Wt2,
                                                  unsigned short* __restrict__ H, int N) {
    __shared__ char XsB[32768];
    __shared__ char WsB[16384];
    const int tid = threadIdx.x;
    const int bm0 = blockIdx.x * 128;
    {
        int k16 = tid & 15, r0 = tid >> 4;
        for (int it = 0; it < 8; ++it) {
            int r = it * 16 + r0;
            int node = min(bm0 + r, N - 1);
            uint4 g = *(const uint4*)(A + (size_t)node * 128 + k16 * 8);
            *(uint4*)(XsB + r * 256 + ((k16 * 16) ^ ((r & 7) << 4))) = g;
        }
    }
    {
        const uint4* src = (const uint4*)Wt2;
        for (int t = 0; t < 4; ++t) {
            int i = t * 256 + tid;
            int n = i >> 4, kb = (i & 15) * 16;
            *(uint4*)(WsB + n * 256 + (kb ^ ((n & 7) << 4))) = src[i];
        }
    }
    __syncthreads();
    const int w = tid >> 6, l = tid & 63;
    const int lr = l & 15, lg = l >> 4;
    f32x4 acc[2][4] = {};
#pragma unroll
    for (int kk = 0; kk < 4; ++kk) {
        bf16x8 a[2], b[4];
#pragma unroll
        for (int mt = 0; mt < 2; ++mt) {
            int r = w * 32 + mt * 16 + lr;
            a[mt] = *(const bf16x8*)(XsB + r * 256 + ((kk * 64 + lg * 16) ^ ((r & 7) << 4)));
        }
#pragma unroll
        for (int nt = 0; nt < 4; ++nt) {
            int n = nt * 16 + lr;
            b[nt] = *(const bf16x8*)(WsB + n * 256 + ((kk * 64 + lg * 16) ^ ((n & 7) << 4)));
        }
#pragma unroll
        for (int mt = 0; mt < 2; ++mt)
#pragma unroll
            for (int nt = 0; nt < 4; ++nt)
                acc[mt][nt] = __builtin_amdgcn_mfma_f32_16x16x32_bf16(a[mt], b[nt], acc[mt][nt], 0, 0, 0);
    }
#pragma unroll
    for (int mt = 0; mt < 2; ++mt)
#pragma unroll
        for (int reg = 0; reg < 4; ++reg) {
            int node = bm0 + w * 32 + mt * 16 + lg * 4 + reg;
            if (node < N) {
#pragma unroll
                for (int nt = 0; nt < 4; ++nt)
                    H[(size_t)node * 64 + nt * 16 + lr] = (unsigned short)f2bf(acc[mt][nt][reg]);
            }
        }
}

// ---- deg from CSR segment sum; dinv = rsqrt(deg + 1). 16 lanes per node ----
__global__ __launch_bounds__(256) void deg_dinv_kernel(const int* __restrict__ rowPtr,
                                                       const unsigned* __restrict__ csru,
                                                       float* __restrict__ dinv, int N) {
    int idx = blockIdx.x * 256 + threadIdx.x;
    int n = idx >> 4, l = idx & 15;
    if (n >= N) return;
    int beg = rowPtr[n], end = rowPtr[n + 1];
    float s = 0.f;
    for (int i = beg + l; i < end; i += 16) s += bf2f(csru[i] & 0xffffu);
#pragma unroll
    for (int off = 8; off; off >>= 1) s += __shfl_xor(s, off, 16);
    if (l == 0) dinv[n] = rsqrtf(s + 1.0f);
}

// ---- layer 1 gather: one wave/node, 2 edges per slot (32-lane halves, uint2/lane) ----
__global__ __launch_bounds__(256) void agg_gather1(const int* __restrict__ rowPtr,
                                                   const unsigned* __restrict__ csru,  // (src<<16)|bf16(ew)
                                                   const uint2* __restrict__ H1u2,     // [N][32] bf16x4
                                                   const float* __restrict__ dinv,
                                                   const float4* __restrict__ b4,
                                                   uint2* __restrict__ out1, int N) {
    int n = (blockIdx.x * 256 + threadIdx.x) >> 6;
    int l = threadIdx.x & 63;
    if (n >= N) return;
    const int half = l >> 5, sub = l & 31;
    float a0 = 0.f, a1 = 0.f, a2 = 0.f, a3 = 0.f;
    int beg = rowPtr[n], end = rowPtr[n + 1];
    for (int j = beg; j < end; j += 8) {
#pragma unroll
        for (int q = 0; q < 4; ++q) {
            int e = j + 2 * q + half;
            unsigned p = e < end ? csru[e] : 0u;
            int src = p >> 16;
            float w = e < end ? bf2f(p & 0xffffu) * dinv[src] : 0.f;
            uint2 v = H1u2[(size_t)src * 32 + sub];
            a0 += w * bf2f(v.x & 0xffffu);
            a1 += w * bf2f(v.x >> 16);
            a2 += w * bf2f(v.y & 0xffffu);
            a3 += w * bf2f(v.y >> 16);
        }
    }
    // merge the two halves (each processed interleaved edges of the same node)
    a0 += __shfl_xor(a0, 32, 64);
    a1 += __shfl_xor(a1, 32, 64);
    a2 += __shfl_xor(a2, 32, 64);
    a3 += __shfl_xor(a3, 32, 64);
    if (half == 0) {
        float dn = dinv[n];
        float s = dn * dn;
        uint2 hv = H1u2[(size_t)n * 32 + sub];
        float4 bb = b4[sub];
        float o0 = fmaxf(fmaf(dn, a0, s * bf2f(hv.x & 0xffffu)) + bb.x, 0.f);
        float o1 = fmaxf(fmaf(dn, a1, s * bf2f(hv.x >> 16)) + bb.y, 0.f);
        float o2 = fmaxf(fmaf(dn, a2, s * bf2f(hv.y & 0xffffu)) + bb.z, 0.f);
        float o3 = fmaxf(fmaf(dn, a3, s * bf2f(hv.y >> 16)) + bb.w, 0.f);
        out1[(size_t)n * 32 + sub] = make_uint2(f2bf(o0) | (f2bf(o1) << 16),
                                                f2bf(o2) | (f2bf(o3) << 16));
    }
}

// ---- layer 2 gather (bf16 H3 [N][64]) + on-fly norm + self + bias + L2 norm ----
__global__ __launch_bounds__(256) void agg_gather2(const int* __restrict__ rowPtr,
                                                   const unsigned* __restrict__ csru,
                                                   const unsigned* __restrict__ H3u,  // [N][32] bf16x2
                                                   const float* __restrict__ dinv,
                                                   const float2* __restrict__ b2,
                                                   float2* __restrict__ out2, int N) {
    int n = (blockIdx.x * 256 + threadIdx.x) >> 5;
    int l = threadIdx.x & 31;
    if (n >= N) return;
    float dn = dinv[n];
    float accx = 0.f, accy = 0.f;
    int beg = rowPtr[n], end = rowPtr[n + 1];
    int j = beg;
    for (; j + 4 <= end; j += 4) {
        unsigned p0 = csru[j + 0], p1 = csru[j + 1], p2 = csru[j + 2], p3 = csru[j + 3];
        int s0 = p0 >> 16, s1 = p1 >> 16, s2 = p2 >> 16, s3 = p3 >> 16;
        float w0 = bf2f(p0 & 0xffffu) * dinv[s0];
        float w1 = bf2f(p1 & 0xffffu) * dinv[s1];
        float w2 = bf2f(p2 & 0xffffu) * dinv[s2];
        float w3 = bf2f(p3 & 0xffffu) * dinv[s3];
        unsigned v0 = H3u[(size_t)s0 * 32 + l];
        unsigned v1 = H3u[(size_t)s1 * 32 + l];
        unsigned v2 = H3u[(size_t)s2 * 32 + l];
        unsigned v3 = H3u[(size_t)s3 * 32 + l];
        accx += w0 * bf2f(v0 & 0xffffu); accy += w0 * bf2f(v0 >> 16);
        accx += w1 * bf2f(v1 & 0xffffu); accy += w1 * bf2f(v1 >> 16);
        accx += w2 * bf2f(v2 & 0xffffu); accy += w2 * bf2f(v2 >> 16);
        accx += w3 * bf2f(v3 & 0xffffu); accy += w3 * bf2f(v3 >> 16);
    }
    for (; j < end; ++j) {
        unsigned p = csru[j];
        int s0 = p >> 16;
        float w = bf2f(p & 0xffffu) * dinv[s0];
        unsigned v = H3u[(size_t)s0 * 32 + l];
        accx += w * bf2f(v & 0xffffu); accy += w * bf2f(v >> 16);
    }
    unsigned hv = H3u[(size_t)n * 32 + l];
    float2 bb = b2[l];
    float s = dn * dn;
    float vx = fmaf(dn, accx, s * bf2f(hv & 0xffffu)) + bb.x;
    float vy = fmaf(dn, accy, s * bf2f(hv >> 16)) + bb.y;
    float ss = vx * vx + vy * vy;
#pragma unroll
    for (int off = 16; off; off >>= 1) ss += __shfl_xor(ss, off, 64);  // stays in 32-group
    float scale = 1.0f / fmaxf(sqrtf(ss), 1e-12f);
    out2[(size_t)n * 32 + l] = make_float2(vx * scale, vy * scale);
}

extern "C" void kernel_launch(void* const* d_in, const int* in_sizes, int n_in,
                              void* d_out, int out_size, void* d_ws, size_t ws_size,
                              hipStream_t stream) {
    const float* x  = (const float*)d_in[0];
    const int*   ei = (const int*)d_in[1];
    const float* ew = (const float*)d_in[2];
    const float* W1 = (const float*)d_in[3];
    const float* b1 = (const float*)d_in[4];
    const float* W2 = (const float*)d_in[5];
    const float* b2 = (const float*)d_in[6];
    float* out = (float*)d_out;
    const int N = in_sizes[0] / NF;
    const int E = in_sizes[2];
    const int* row = ei;
    const int* col = ei + E;
    const int NB2 = (N + 255) / 256;
    const int SL = (E + SLICES - 1) / SLICES;
    const int nh = (N + 1) / 2;

    char* ws = (char*)d_ws;
    size_t off = 0;
    auto take = [&](size_t bytes) {
        char* p = ws + off;
        off = (off + bytes + 255) & ~(size_t)255;
        return p;
    };
    float* dinv   = (float*)take((size_t)N * 4);
    int*   rowPtr = (int*)  take((size_t)(N + 1) * 4);
    unsigned short* eoff16 = (unsigned short*)take((size_t)E * 2);
    int*   bsum   = (int*)  take((size_t)(NB2 + 1) * 4);
    unsigned short* C16    = (unsigned short*)take((size_t)SLICES * N * 2);
    unsigned* csru = (unsigned*)take((size_t)E * 4);
    unsigned short* Xb   = (unsigned short*)take((size_t)N * NF * 2);  // bf16 X
    unsigned short* H1   = (unsigned short*)take((size_t)N * NF * 2);  // bf16 [N][128]; reused as H3
    unsigned short* relu = (unsigned short*)take((size_t)N * NF * 2);  // bf16 [N][128]
    unsigned short* Wt1  = (unsigned short*)take(128 * 128 * 2);
    unsigned short* Wt2  = (unsigned short*)take(64 * 128 * 2);
    unsigned short* H3 = H1;   // [N][64] bf16, written after H1 consumed

    // fused prep: count_rank (LDS atomics only) || weight prep || X->bf16 cast
    const int CRB = 2 * SLICES, WTB = 96, XCB = 1024;
    prep_fused<<<CRB + WTB + XCB, 256, 0, stream>>>(col, eoff16, C16, W1, W2, Wt1, Wt2,
                                                    x, (unsigned*)Xb, N, E, SL, nh,
                                                    CRB, WTB, XCB);

    // merged slice-scan + block-scan -> rowPtr
    scanCB<<<NB2, 256, 0, stream>>>(C16, rowPtr, bsum, N);
    scan_sums<<<1, 1, 0, stream>>>(bsum, NB2);
    scan_add<<<(N + 255) / 256, 256, 0, stream>>>(rowPtr, bsum, N, NB2);

    // fused: slice-aligned CSR scatter (4B packed) || MFMA GEMM1 (bf16 in/out, row-major)
    const int SB = 8 * SLICES;
    const int GB = (N + 63) / 64;
    scatter_gemm1_fused<<<SB + GB, 256, 0, stream>>>(row, col, ew, rowPtr, C16, eoff16,
                                                     csru, Xb, Wt1, H1, N, E, SL, SB);

    // degree -> dinv (weights normalized on the fly in agg kernels)
    deg_dinv_kernel<<<(N * 16 + 255) / 256, 256, 0, stream>>>(rowPtr, csru, dinv, N);

    // layer 1 aggregation (2 edges/slot wave gathers) + bias + relu -> bf16 [N][128]
    agg_gather1<<<(N * 64 + 255) / 256, 256, 0, stream>>>(rowPtr, csru, (const uint2*)H1,
                                                          dinv, (const float4*)b1,
                                                          (uint2*)relu, N);

    // layer 2: MFMA GEMM ; gather + bias + l2norm
    gemm2_mfma<<<(N + 127) / 128, 256, 0, stream>>>(relu, Wt2, H3, N);
    agg_gather2<<<(N * 32 + 255) / 256, 256, 0, stream>>>(rowPtr, csru, (const unsigned*)H3,
                                                          dinv, (const float2*)b2,
                                                          (float2*)out, N);
}

// Round 15
// 161.159 us; speedup vs baseline: 1.1310x; 1.1310x over previous
//
#include <hip/hip_runtime.h>

#define NF 128   // in/hidden features
#define NC 64    // classes
#define SLICES 64

typedef short bf16x8 __attribute__((ext_vector_type(8)));
typedef float f32x4 __attribute__((ext_vector_type(4)));

__device__ __forceinline__ unsigned f2bf(float f) {   // fp32 -> bf16 (RTN)
    unsigned u = __float_as_uint(f);
    return (u + 0x7FFFu + ((u >> 16) & 1u)) >> 16;
}
__device__ __forceinline__ float bf2f(unsigned h) { return __uint_as_float(h << 16); }

// ---- fused prep: count_rank blocks + weight-transpose blocks + X->bf16 cast blocks ----
__global__ __launch_bounds__(256) void prep_fused(const int* __restrict__ col,
                                                  unsigned short* __restrict__ eoff16,
                                                  unsigned short* __restrict__ C16,
                                                  const float* __restrict__ W1,
                                                  const float* __restrict__ W2,
                                                  unsigned short* __restrict__ Wt1,
                                                  unsigned short* __restrict__ Wt2,
                                                  const float* __restrict__ X,
                                                  unsigned* __restrict__ Xb2,
                                                  int N, int E, int SL, int nh,
                                                  int CRB, int WTB, int XCB) {
    __shared__ unsigned hist[12544];
    const int b = blockIdx.x;
    const int tid = threadIdx.x;
    if (b < CRB) {
        const int j = b >> 1;
        const int h = b & 1;
        const int nlo = h * nh;
        const int nhi = min(N, nlo + nh);
        const int words = (nhi - nlo + 1) >> 1;
        for (int i = tid; i < words; i += 256) hist[i] = 0;
        __syncthreads();
        const int e0 = j * SL, e1 = min(E, e0 + SL);
        for (int e = e0 + tid; e < e1; e += 256) {
            int c = col[e];
            if (c >= nlo && c < nhi) {
                int cl = c - nlo;
                unsigned sh = (cl & 1) * 16;
                unsigned old = atomicAdd(&hist[cl >> 1], 1u << sh);
                eoff16[e] = (unsigned short)((old >> sh) & 0xffffu);
            }
        }
        __syncthreads();
        unsigned* Cw = (unsigned*)(C16 + (size_t)j * N + nlo);
        for (int i = tid; i < words; i += 256) Cw[i] = hist[i];
    } else if (b < CRB + WTB) {
        int i = (b - CRB) * 256 + tid;
        if (i < 128 * 128) {
            int k = i >> 7, n = i & 127;
            Wt1[n * 128 + k] = (unsigned short)f2bf(W1[i]);
        } else {
            int j = i - 128 * 128;
            if (j < 128 * 64) {
                int k = j >> 6, n = j & 63;
                Wt2[n * 128 + k] = (unsigned short)f2bf(W2[j]);
            }
        }
    } else {
        const float4* X4 = (const float4*)X;
        uint2* O = (uint2*)Xb2;
        int items = N * 32;
        for (int i = (b - CRB - WTB) * 256 + tid; i < items; i += XCB * 256) {
            float4 v = X4[i];
            O[i] = make_uint2(f2bf(v.x) | (f2bf(v.y) << 16),
                              f2bf(v.z) | (f2bf(v.w) << 16));
        }
    }
}

// ---- merged: per-node slice scan (C16 in place) + 256-node block scan -> excl, bsum ----
__global__ __launch_bounds__(256) void scanCB(unsigned short* __restrict__ C16,
                                              int* __restrict__ excl,
                                              int* __restrict__ bsum, int N) {
    __shared__ int sh[256];
    int t = threadIdx.x;
    int n = blockIdx.x * 256 + t;
    int run = 0;
    if (n < N) {
#pragma unroll 4
        for (int j = 0; j < SLICES; ++j) {
            size_t idx = (size_t)j * N + n;
            int v = C16[idx];
            C16[idx] = (unsigned short)run;
            run += v;
        }
    }
    sh[t] = run;
    __syncthreads();
    for (int off = 1; off < 256; off <<= 1) {
        int x = (t >= off) ? sh[t - off] : 0;
        __syncthreads();
        sh[t] += x;
        __syncthreads();
    }
    int incl = sh[t];
    if (t == 255) bsum[blockIdx.x] = incl;
    if (n < N) excl[n] = incl - run;
}

__global__ void scan_sums(int* __restrict__ bsum, int nb) {
    int run = 0;
    for (int i = 0; i < nb; ++i) { int v = bsum[i]; bsum[i] = run; run += v; }
    bsum[nb] = run;
}

__global__ __launch_bounds__(256) void scan_add(int* __restrict__ excl,
                                                const int* __restrict__ bsum,
                                                int N, int nb) {
    int i = blockIdx.x * 256 + threadIdx.x;
    if (i < N) excl[i] += bsum[i >> 8];
    if (i == 0) excl[N] = bsum[nb];
}

// ---- fused: slice-aligned scatter (packed 4B entries, no atomics) + MFMA gemm1 ----
__global__ __launch_bounds__(256) void scatter_gemm1_fused(const int* __restrict__ row,
                                                           const int* __restrict__ col,
                                                           const float* __restrict__ ew,
                                                           const int* __restrict__ rowPtr,
                                                           const unsigned short* __restrict__ Coff16,
                                                           const unsigned short* __restrict__ eoff16,
                                                           unsigned* __restrict__ csru,
                                                           const unsigned short* __restrict__ Xb,  // [N][128] bf16
                                                           const unsigned short* __restrict__ Wt1,
                                                           unsigned short* __restrict__ H,  // [N][128] bf16
                                                           int N, int E, int SL, int SB) {
    __shared__ char XsB[16384];   // 64 rows x 128 k bf16, XOR-swizzled
    __shared__ char WsB[32768];   // 128 n  x 128 k bf16, XOR-swizzled
    const int tid = threadIdx.x;
    if ((int)blockIdx.x < SB) {
        const int j = blockIdx.x >> 3;
        const int sub = blockIdx.x & 7;
        const int e0 = j * SL, e1 = min(E, e0 + SL);
        const int per = ((e1 - e0) + 7) >> 3;
        const int lo = min(e1, e0 + sub * per);
        const int hi = min(e1, lo + per);
        const unsigned short* Crow = Coff16 + (size_t)j * N;
        for (int e = lo + tid; e < hi; e += 256) {
            int c = col[e];
            int idx = rowPtr[c] + (int)Crow[c] + (int)eoff16[e];
            csru[idx] = ((unsigned)row[e] << 16) | f2bf(ew[e]);
        }
        return;
    }
    const int bm0 = ((int)blockIdx.x - SB) * 64;
    {   // stage Xb rows (bf16): 64 rows x 16 uint4; 4 uint4 per thread
        int r = tid >> 2, q4 = (tid & 3) * 4;
        const uint4* src = (const uint4*)(Xb + (size_t)min(bm0 + r, N - 1) * 128);
#pragma unroll
        for (int qq = 0; qq < 4; ++qq) {
            int kb = (q4 + qq) * 16;
            *(uint4*)(XsB + r * 256 + (kb ^ ((r & 7) << 4))) = src[q4 + qq];
        }
    }
    {   // stage Wt1 (bf16): 2048 uint4, 8 per thread
        const uint4* src = (const uint4*)Wt1;
#pragma unroll
        for (int t = 0; t < 8; ++t) {
            int i = t * 256 + tid;
            int n = i >> 4, kb = (i & 15) * 16;
            *(uint4*)(WsB + n * 256 + (kb ^ ((n & 7) << 4))) = src[i];
        }
    }
    __syncthreads();
    const int w = tid >> 6, l = tid & 63;
    const int lr = l & 15, lg = l >> 4;
    f32x4 acc[8] = {};
#pragma unroll
    for (int kk = 0; kk < 4; ++kk) {
        int r = w * 16 + lr;
        bf16x8 a = *(const bf16x8*)(XsB + r * 256 + ((kk * 64 + lg * 16) ^ ((r & 7) << 4)));
        bf16x8 b[8];
#pragma unroll
        for (int nt = 0; nt < 8; ++nt) {
            int n = nt * 16 + lr;
            b[nt] = *(const bf16x8*)(WsB + n * 256 + ((kk * 64 + lg * 16) ^ ((n & 7) << 4)));
        }
#pragma unroll
        for (int nt = 0; nt < 8; ++nt)
            acc[nt] = __builtin_amdgcn_mfma_f32_16x16x32_bf16(a, b[nt], acc[nt], 0, 0, 0);
    }
#pragma unroll
    for (int reg = 0; reg < 4; ++reg) {
        int node = bm0 + w * 16 + lg * 4 + reg;
        if (node < N) {
#pragma unroll
            for (int nt = 0; nt < 8; ++nt)
                H[(size_t)node * 128 + nt * 16 + lr] = (unsigned short)f2bf(acc[nt][reg]);
        }
    }
}

// ---- MFMA gemm2: H3[N x 64 bf16] = A(bf16 [N][128]) @ W2 ----
__global__ __launch_bounds__(256) void gemm2_mfma(const unsigned short* __restrict__ A,
                                                  const unsigned short* __restrict__ Wt2,
                                                  unsigned short* __restrict__ H, int N) {
    __shared__ char XsB[32768];
    __shared__ char WsB[16384];
    const int tid = threadIdx.x;
    const int bm0 = blockIdx.x * 128;
    {
        int k16 = tid & 15, r0 = tid >> 4;
        for (int it = 0; it < 8; ++it) {
            int r = it * 16 + r0;
            int node = min(bm0 + r, N - 1);
            uint4 g = *(const uint4*)(A + (size_t)node * 128 + k16 * 8);
            *(uint4*)(XsB + r * 256 + ((k16 * 16) ^ ((r & 7) << 4))) = g;
        }
    }
    {
        const uint4* src = (const uint4*)Wt2;
        for (int t = 0; t < 4; ++t) {
            int i = t * 256 + tid;
            int n = i >> 4, kb = (i & 15) * 16;
            *(uint4*)(WsB + n * 256 + (kb ^ ((n & 7) << 4))) = src[i];
        }
    }
    __syncthreads();
    const int w = tid >> 6, l = tid & 63;
    const int lr = l & 15, lg = l >> 4;
    f32x4 acc[2][4] = {};
#pragma unroll
    for (int kk = 0; kk < 4; ++kk) {
        bf16x8 a[2], b[4];
#pragma unroll
        for (int mt = 0; mt < 2; ++mt) {
            int r = w * 32 + mt * 16 + lr;
            a[mt] = *(const bf16x8*)(XsB + r * 256 + ((kk * 64 + lg * 16) ^ ((r & 7) << 4)));
        }
#pragma unroll
        for (int nt = 0; nt < 4; ++nt) {
            int n = nt * 16 + lr;
            b[nt] = *(const bf16x8*)(WsB + n * 256 + ((kk * 64 + lg * 16) ^ ((n & 7) << 4)));
        }
#pragma unroll
        for (int mt = 0; mt < 2; ++mt)
#pragma unroll
            for (int nt = 0; nt < 4; ++nt)
                acc[mt][nt] = __builtin_amdgcn_mfma_f32_16x16x32_bf16(a[mt], b[nt], acc[mt][nt], 0, 0, 0);
    }
#pragma unroll
    for (int mt = 0; mt < 2; ++mt)
#pragma unroll
        for (int reg = 0; reg < 4; ++reg) {
            int node = bm0 + w * 32 + mt * 16 + lg * 4 + reg;
            if (node < N) {
#pragma unroll
                for (int nt = 0; nt < 4; ++nt)
                    H[(size_t)node * 64 + nt * 16 + lr] = (unsigned short)f2bf(acc[mt][nt][reg]);
            }
        }
}

// ---- deg from CSR segment sum; dinv = rsqrt(deg + 1). 16 lanes per node ----
__global__ __launch_bounds__(256) void deg_dinv_kernel(const int* __restrict__ rowPtr,
                                                       const unsigned* __restrict__ csru,
                                                       float* __restrict__ dinv, int N) {
    int idx = blockIdx.x * 256 + threadIdx.x;
    int n = idx >> 4, l = idx & 15;
    if (n >= N) return;
    int beg = rowPtr[n], end = rowPtr[n + 1];
    float s = 0.f;
    for (int i = beg + l; i < end; i += 16) s += bf2f(csru[i] & 0xffffu);
#pragma unroll
    for (int off = 8; off; off >>= 1) s += __shfl_xor(s, off, 16);
    if (l == 0) dinv[n] = rsqrtf(s + 1.0f);
}

// ---- layer 1 gather (bf16 H1, packed 4B csr, unroll-4, on-fly dinv) -> bf16 out ----
__global__ __launch_bounds__(256) void agg_gather1(const int* __restrict__ rowPtr,
                                                   const unsigned* __restrict__ csru,
                                                   const unsigned* __restrict__ H1u,  // [N][64] bf16x2
                                                   const float* __restrict__ dinv,
                                                   const float2* __restrict__ b2,
                                                   unsigned* __restrict__ out1, int N) {
    int n = (blockIdx.x * 256 + threadIdx.x) >> 6;
    int lane = threadIdx.x & 63;
    if (n >= N) return;
    float dn = dinv[n];
    float accx = 0.f, accy = 0.f;
    int beg = rowPtr[n], end = rowPtr[n + 1];
    int j = beg;
    for (; j + 4 <= end; j += 4) {
        unsigned p0 = csru[j + 0], p1 = csru[j + 1], p2 = csru[j + 2], p3 = csru[j + 3];
        int s0 = p0 >> 16, s1 = p1 >> 16, s2 = p2 >> 16, s3 = p3 >> 16;
        float w0 = bf2f(p0 & 0xffffu) * dinv[s0];
        float w1 = bf2f(p1 & 0xffffu) * dinv[s1];
        float w2 = bf2f(p2 & 0xffffu) * dinv[s2];
        float w3 = bf2f(p3 & 0xffffu) * dinv[s3];
        unsigned v0 = H1u[(size_t)s0 * 64 + lane];
        unsigned v1 = H1u[(size_t)s1 * 64 + lane];
        unsigned v2 = H1u[(size_t)s2 * 64 + lane];
        unsigned v3 = H1u[(size_t)s3 * 64 + lane];
        accx += w0 * bf2f(v0 & 0xffffu); accy += w0 * bf2f(v0 >> 16);
        accx += w1 * bf2f(v1 & 0xffffu); accy += w1 * bf2f(v1 >> 16);
        accx += w2 * bf2f(v2 & 0xffffu); accy += w2 * bf2f(v2 >> 16);
        accx += w3 * bf2f(v3 & 0xffffu); accy += w3 * bf2f(v3 >> 16);
    }
    for (; j < end; ++j) {
        unsigned p = csru[j];
        int s0 = p >> 16;
        float w = bf2f(p & 0xffffu) * dinv[s0];
        unsigned v = H1u[(size_t)s0 * 64 + lane];
        accx += w * bf2f(v & 0xffffu); accy += w * bf2f(v >> 16);
    }
    unsigned hv = H1u[(size_t)n * 64 + lane];
    float2 bb = b2[lane];
    float s = dn * dn;
    float ox = fmaxf(fmaf(dn, accx, s * bf2f(hv & 0xffffu)) + bb.x, 0.f);
    float oy = fmaxf(fmaf(dn, accy, s * bf2f(hv >> 16)) + bb.y, 0.f);
    out1[(size_t)n * 64 + lane] = f2bf(ox) | (f2bf(oy) << 16);
}

// ---- layer 2 gather (bf16 H3, packed csr, unroll-4, on-fly dinv) + L2 norm ----
__global__ __launch_bounds__(256) void agg_gather2(const int* __restrict__ rowPtr,
                                                   const unsigned* __restrict__ csru,
                                                   const unsigned* __restrict__ H3u,  // [N][32] bf16x2
                                                   const float* __restrict__ dinv,
                                                   const float2* __restrict__ b2,
                                                   float2* __restrict__ out2, int N) {
    int n = (blockIdx.x * 256 + threadIdx.x) >> 5;
    int l = threadIdx.x & 31;
    if (n >= N) return;
    float dn = dinv[n];
    float accx = 0.f, accy = 0.f;
    int beg = rowPtr[n], end = rowPtr[n + 1];
    int j = beg;
    for (; j + 4 <= end; j += 4) {
        unsigned p0 = csru[j + 0], p1 = csru[j + 1], p2 = csru[j + 2], p3 = csru[j + 3];
        int s0 = p0 >> 16, s1 = p1 >> 16, s2 = p2 >> 16, s3 = p3 >> 16;
        float w0 = bf2f(p0 & 0xffffu) * dinv[s0];
        float w1 = bf2f(p1 & 0xffffu) * dinv[s1];
        float w2 = bf2f(p2 & 0xffffu) * dinv[s2];
        float w3 = bf2f(p3 & 0xffffu) * dinv[s3];
        unsigned v0 = H3u[(size_t)s0 * 32 + l];
        unsigned v1 = H3u[(size_t)s1 * 32 + l];
        unsigned v2 = H3u[(size_t)s2 * 32 + l];
        unsigned v3 = H3u[(size_t)s3 * 32 + l];
        accx += w0 * bf2f(v0 & 0xffffu); accy += w0 * bf2f(v0 >> 16);
        accx += w1 * bf2f(v1 & 0xffffu); accy += w1 * bf2f(v1 >> 16);
        accx += w2 * bf2f(v2 & 0xffffu); accy += w2 * bf2f(v2 >> 16);
        accx += w3 * bf2f(v3 & 0xffffu); accy += w3 * bf2f(v3 >> 16);
    }
    for (; j < end; ++j) {
        unsigned p = csru[j];
        int s0 = p >> 16;
        float w = bf2f(p & 0xffffu) * dinv[s0];
        unsigned v = H3u[(size_t)s0 * 32 + l];
        accx += w * bf2f(v & 0xffffu); accy += w * bf2f(v >> 16);
    }
    unsigned hv = H3u[(size_t)n * 32 + l];
    float2 bb = b2[l];
    float s = dn * dn;
    float vx = fmaf(dn, accx, s * bf2f(hv & 0xffffu)) + bb.x;
    float vy = fmaf(dn, accy, s * bf2f(hv >> 16)) + bb.y;
    float ss = vx * vx + vy * vy;
#pragma unroll
    for (int off = 16; off; off >>= 1) ss += __shfl_xor(ss, off, 64);  // stays in 32-group
    float scale = 1.0f / fmaxf(sqrtf(ss), 1e-12f);
    out2[(size_t)n * 32 + l] = make_float2(vx * scale, vy * scale);
}

extern "C" void kernel_launch(void* const* d_in, const int* in_sizes, int n_in,
                              void* d_out, int out_size, void* d_ws, size_t ws_size,
                              hipStream_t stream) {
    const float* x  = (const float*)d_in[0];
    const int*   ei = (const int*)d_in[1];
    const float* ew = (const float*)d_in[2];
    const float* W1 = (const float*)d_in[3];
    const float* b1 = (const float*)d_in[4];
    const float* W2 = (const float*)d_in[5];
    const float* b2 = (const float*)d_in[6];
    float* out = (float*)d_out;
    const int N = in_sizes[0] / NF;
    const int E = in_sizes[2];
    const int* row = ei;
    const int* col = ei + E;
    const int NB2 = (N + 255) / 256;
    const int SL = (E + SLICES - 1) / SLICES;
    const int nh = (N + 1) / 2;

    char* ws = (char*)d_ws;
    size_t off = 0;
    auto take = [&](size_t bytes) {
        char* p = ws + off;
        off = (off + bytes + 255) & ~(size_t)255;
        return p;
    };
    float* dinv   = (float*)take((size_t)N * 4);
    int*   rowPtr = (int*)  take((size_t)(N + 1) * 4);
    unsigned short* eoff16 = (unsigned short*)take((size_t)E * 2);
    int*   bsum   = (int*)  take((size_t)(NB2 + 1) * 4);
    unsigned short* C16    = (unsigned short*)take((size_t)SLICES * N * 2);
    unsigned* csru = (unsigned*)take((size_t)E * 4);
    unsigned short* Xb   = (unsigned short*)take((size_t)N * NF * 2);  // bf16 X
    unsigned short* H1   = (unsigned short*)take((size_t)N * NF * 2);  // bf16 [N][128]; reused as H3
    unsigned short* relu = (unsigned short*)take((size_t)N * NF * 2);  // bf16 [N][128]
    unsigned short* Wt1  = (unsigned short*)take(128 * 128 * 2);
    unsigned short* Wt2  = (unsigned short*)take(64 * 128 * 2);
    unsigned short* H3 = H1;   // [N][64] bf16, written after H1 consumed

    // fused prep: count_rank (LDS atomics only) || weight prep || X->bf16 cast
    const int CRB = 2 * SLICES, WTB = 96, XCB = 1024;
    prep_fused<<<CRB + WTB + XCB, 256, 0, stream>>>(col, eoff16, C16, W1, W2, Wt1, Wt2,
                                                    x, (unsigned*)Xb, N, E, SL, nh,
                                                    CRB, WTB, XCB);

    // merged slice-scan + block-scan -> rowPtr
    scanCB<<<NB2, 256, 0, stream>>>(C16, rowPtr, bsum, N);
    scan_sums<<<1, 1, 0, stream>>>(bsum, NB2);
    scan_add<<<(N + 255) / 256, 256, 0, stream>>>(rowPtr, bsum, N, NB2);

    // fused: slice-aligned CSR scatter (4B packed) || MFMA GEMM1 (bf16 in/out)
    const int SB = 8 * SLICES;
    const int GB = (N + 63) / 64;
    scatter_gemm1_fused<<<SB + GB, 256, 0, stream>>>(row, col, ew, rowPtr, C16, eoff16,
                                                     csru, Xb, Wt1, H1, N, E, SL, SB);

    // degree -> dinv (weights normalized on the fly in agg kernels)
    deg_dinv_kernel<<<(N * 16 + 255) / 256, 256, 0, stream>>>(rowPtr, csru, dinv, N);

    // layer 1 aggregation + bias + relu -> bf16 [N][128]
    agg_gather1<<<(N * 64 + 255) / 256, 256, 0, stream>>>(rowPtr, csru, (const unsigned*)H1,
                                                          dinv, (const float2*)b1,
                                                          (unsigned*)relu, N);

    // layer 2: MFMA GEMM ; gather + bias + l2norm
    gemm2_mfma<<<(N + 127) / 128, 256, 0, stream>>>(relu, Wt2, H3, N);
    agg_gather2<<<(N * 32 + 255) / 256, 256, 0, stream>>>(rowPtr, csru, (const unsigned*)H3,
                                                          dinv, (const float2*)b2,
                                                          (float2*)out, N);
}